// Round 1
// baseline (12333.205 us; speedup 1.0000x reference)
//
#include <hip/hip_runtime.h>

// FFJORD: B=4096, D=64, C=16, H=512, NBIJ=2, NSTEPS=8 (RK4).
// Persistent fp32 kernel: 512 blocks x 8 rows, 512 threads, full ODE chain in one launch.
// d_ws holds transposed weights (W2T, W3T, W1yT) rebuilt every launch by prep kernel.

#define ROWS 8
#define NT 512

__device__ __forceinline__ void fma4(float4& acc, float a, const float4 w) {
  acc.x = fmaf(a, w.x, acc.x);
  acc.y = fmaf(a, w.y, acc.y);
  acc.z = fmaf(a, w.z, acc.z);
  acc.w = fmaf(a, w.w, acc.w);
}

// out[rA][j0..j0+3], out[rB][j0..j0+3] accumulated; W has row-stride 512, column offset pre-folded.
__device__ __forceinline__ void gemm2x4(const float* sA, const float* sB,
                                        const float* __restrict__ W, int K,
                                        float4& accA, float4& accB) {
  int k = 0;
  for (; k + 4 <= K; k += 4) {
    float4 a = *(const float4*)(sA + k);
    float4 b = *(const float4*)(sB + k);
    const float* wr = W + (size_t)k * 512;
    float4 w0 = *(const float4*)(wr);
    float4 w1 = *(const float4*)(wr + 512);
    float4 w2 = *(const float4*)(wr + 1024);
    float4 w3 = *(const float4*)(wr + 1536);
    fma4(accA, a.x, w0); fma4(accB, b.x, w0);
    fma4(accA, a.y, w1); fma4(accB, b.y, w1);
    fma4(accA, a.z, w2); fma4(accB, b.z, w2);
    fma4(accA, a.w, w3); fma4(accB, b.w, w3);
  }
  for (; k < K; ++k) {  // tail (K=81 case: k=80)
    float4 w0 = *(const float4*)(W + (size_t)k * 512);
    fma4(accA, sA[k], w0);
    fma4(accB, sB[k], w0);
  }
}

// N=64 GEMMs (f = h2@W3, gz = g1h@W1yT): one output per thread, W row-stride 64, K=512.
__device__ __forceinline__ float gemmN64(const float* s, const float* __restrict__ W, int d) {
  float acc = 0.f;
  for (int k = 0; k < 512; k += 4) {
    float4 a = *(const float4*)(s + k);
    acc = fmaf(a.x, W[(k + 0) * 64 + d], acc);
    acc = fmaf(a.y, W[(k + 1) * 64 + d], acc);
    acc = fmaf(a.z, W[(k + 2) * 64 + d], acc);
    acc = fmaf(a.w, W[(k + 3) * 64 + d], acc);
  }
  return acc;
}

__device__ __forceinline__ float4 tanh4(float4 v) {
  return make_float4(tanhf(v.x), tanhf(v.y), tanhf(v.z), tanhf(v.w));
}

__global__ __launch_bounds__(NT, 4) void ffjord_kernel(
    const float* __restrict__ x, const float* __restrict__ cond, const float* __restrict__ eps,
    const float* __restrict__ W1, const float* __restrict__ b1,
    const float* __restrict__ W2, const float* __restrict__ b2,
    const float* __restrict__ W3, const float* __restrict__ b3,
    const float* __restrict__ W2T, const float* __restrict__ W3T, const float* __restrict__ W1yT,
    float* __restrict__ out) {
  __shared__ float z_s[ROWS][84];     // [y(64) | cond(16) | t(1) | pad(3)]
  __shared__ float h1_s[ROWS][512];
  __shared__ float h2_s[ROWS][512];   // reused as g1h after forward
  __shared__ float g2_s[ROWS][512];
  __shared__ float ycur[ROWS][64];
  __shared__ float ytmp[ROWS][64];    // aug() input
  __shared__ float yacc[ROWS][64];    // RK4 accumulator
  __shared__ float f_s[ROWS][64];
  __shared__ float cond_s[ROWS][16];
  __shared__ float eps_s[ROWS][64];
  __shared__ float ld_row[ROWS];
  __shared__ float l_row[ROWS];
  __shared__ float ldacc[ROWS];

  const int t = threadIdx.x;
  const int row0 = blockIdx.x * ROWS;
  const int r = t >> 6;    // wave index == row (512 threads = 8 waves = 8 rows)
  const int d = t & 63;    // lane == column in D

  // init state
  ycur[r][d] = x[(row0 + r) * 64 + d];
  ytmp[r][d] = ycur[r][d];
  if (t < ROWS * 16) {
    int rr = t >> 4, c = t & 15;
    float cv = cond[(row0 + rr) * 16 + c];
    cond_s[rr][c] = cv;
    z_s[rr][64 + c] = cv;    // cond part of z never changes
  }
  if (t < ROWS) {
    ld_row[t] = 0.f;
    z_s[t][81] = 0.f; z_s[t][82] = 0.f; z_s[t][83] = 0.f;
  }

  const float dt = 0.125f;
  const float toff[4]  = {0.f, 0.5f * dt, 0.5f * dt, dt};
  const float wacc[4]  = {dt / 6.f, dt / 3.f, dt / 3.f, dt / 6.f};
  const float cnext[3] = {0.5f * dt, 0.5f * dt, dt};

  const int rp = t >> 7;          // row-pair (0..3)
  const int cg = t & 127;         // col-group
  const int j0 = cg * 4;
  const int rA = 2 * rp, rB = 2 * rp + 1;

  for (int ib = 0; ib < 2; ++ib) {
    const float* W1b = W1 + ib * 81 * 512;
    const float* b1b = b1 + ib * 512;
    const float* W2b = W2 + ib * 512 * 512;
    const float* b2b = b2 + ib * 512;
    const float* W3b = W3 + ib * 512 * 64;
    const float* b3b = b3 + ib * 64;
    const float* W2Tb = W2T + ib * 512 * 512;
    const float* W3Tb = W3T + ib * 64 * 512;
    const float* W1yTb = W1yT + ib * 512 * 64;

    eps_s[r][d] = eps[((size_t)ib * 4096 + row0 + r) * 64 + d];
    __syncthreads();

    for (int step = 0; step < 8; ++step) {
      const float t0 = step * dt;
      for (int s = 0; s < 4; ++s) {
        const float te = t0 + toff[s];
        // ---- build z (y part + t column) ----
        z_s[r][d] = ytmp[r][d];
        if (t < ROWS) z_s[t][80] = te;
        __syncthreads();

        // ---- GEMM1: h1 = tanh(z @ W1 + b1), K=81 ----
        {
          float4 aA = *(const float4*)(b1b + j0);
          float4 aB = aA;
          gemm2x4(&z_s[rA][0], &z_s[rB][0], W1b + j0, 81, aA, aB);
          *(float4*)(&h1_s[rA][j0]) = tanh4(aA);
          *(float4*)(&h1_s[rB][j0]) = tanh4(aB);
        }
        __syncthreads();

        // ---- GEMM2: h2 = tanh(h1 @ W2 + b2), K=512 ----
        {
          float4 aA = *(const float4*)(b2b + j0);
          float4 aB = aA;
          gemm2x4(&h1_s[rA][0], &h1_s[rB][0], W2b + j0, 512, aA, aB);
          *(float4*)(&h2_s[rA][j0]) = tanh4(aA);
          *(float4*)(&h2_s[rB][j0]) = tanh4(aB);
        }
        __syncthreads();

        // ---- GEMM3f: f = h2 @ W3 + b3 (N=64) ; GEMM3b: g2h = (eps @ W3T) * (1-h2^2) ----
        f_s[r][d] = b3b[d] + gemmN64(&h2_s[r][0], W3b, d);
        {
          float4 aA = make_float4(0.f, 0.f, 0.f, 0.f);
          float4 aB = aA;
          gemm2x4(&eps_s[rA][0], &eps_s[rB][0], W3Tb + j0, 64, aA, aB);
          float4 hA = *(const float4*)(&h2_s[rA][j0]);
          float4 hB = *(const float4*)(&h2_s[rB][j0]);
          aA.x *= (1.f - hA.x * hA.x); aA.y *= (1.f - hA.y * hA.y);
          aA.z *= (1.f - hA.z * hA.z); aA.w *= (1.f - hA.w * hA.w);
          aB.x *= (1.f - hB.x * hB.x); aB.y *= (1.f - hB.y * hB.y);
          aB.z *= (1.f - hB.z * hB.z); aB.w *= (1.f - hB.w * hB.w);
          *(float4*)(&g2_s[rA][j0]) = aA;
          *(float4*)(&g2_s[rB][j0]) = aB;
        }
        __syncthreads();

        // ---- GEMM4b: g1h = (g2h @ W2T) * (1-h1^2)  -> stored into h2_s ----
        {
          float4 aA = make_float4(0.f, 0.f, 0.f, 0.f);
          float4 aB = aA;
          gemm2x4(&g2_s[rA][0], &g2_s[rB][0], W2Tb + j0, 512, aA, aB);
          float4 hA = *(const float4*)(&h1_s[rA][j0]);
          float4 hB = *(const float4*)(&h1_s[rB][j0]);
          aA.x *= (1.f - hA.x * hA.x); aA.y *= (1.f - hA.y * hA.y);
          aA.z *= (1.f - hA.z * hA.z); aA.w *= (1.f - hA.w * hA.w);
          aB.x *= (1.f - hB.x * hB.x); aB.y *= (1.f - hB.y * hB.y);
          aB.z *= (1.f - hB.z * hB.z); aB.w *= (1.f - hB.w * hB.w);
          *(float4*)(&h2_s[rA][j0]) = aA;
          *(float4*)(&h2_s[rB][j0]) = aB;
        }
        __syncthreads();

        // ---- GEMM5b: gz = g1h @ W1yT (N=64), l = sum(gz * eps) per row ----
        {
          float gz = gemmN64(&h2_s[r][0], W1yTb, d);
          float p = gz * eps_s[r][d];
          for (int off = 32; off; off >>= 1) p += __shfl_down(p, off);
          if (d == 0) l_row[r] = p;
        }
        __syncthreads();

        // ---- RK4 state update (each thread owns (r,d)) ----
        {
          float fv = f_s[r][d];
          if (s == 0)      yacc[r][d] = ycur[r][d] + wacc[0] * fv;
          else if (s < 3)  yacc[r][d] += wacc[s] * fv;
          if (s < 3) {
            ytmp[r][d] = ycur[r][d] + cnext[s] * fv;
          } else {
            float yn = yacc[r][d] + wacc[3] * fv;
            ycur[r][d] = yn;
            ytmp[r][d] = yn;
          }
          if (d == 0) {
            float lv = l_row[r];
            if (s == 0)      ldacc[r] = wacc[0] * lv;
            else if (s < 3)  ldacc[r] += wacc[s] * lv;
            else             ld_row[r] += ldacc[r] + wacc[3] * lv;
          }
        }
        // no barrier needed: next z-build writes are thread-own elements; barrier precedes GEMM1
      }
    }
    __syncthreads();
  }

  // epilogue: out[b][0:64] = y, out[b][64] = ld
  out[(size_t)(row0 + r) * 65 + d] = ycur[r][d];
  if (d == 0) out[(size_t)(row0 + r) * 65 + 64] = ld_row[r];
}

// Build transposed weights in workspace: W2T[ib][k][j]=W2[ib][j][k]; W3T[ib][d][h]=W3[ib][h][d];
// W1yT[ib][k][i]=W1[ib][i][k] (i<64 only — the y-slice of W1^T).
__global__ void transpose_prep(const float* __restrict__ W1, const float* __restrict__ W2,
                               const float* __restrict__ W3,
                               float* __restrict__ W2T, float* __restrict__ W3T,
                               float* __restrict__ W1yT) {
  int idx = blockIdx.x * 256 + threadIdx.x;
  if (idx < 2 * 512 * 512) {
    int ib = idx >> 18;
    int rem = idx & 262143;
    int k = rem >> 9, j = rem & 511;
    W2T[idx] = W2[ib * 262144 + j * 512 + k];
  } else if (idx < 2 * 512 * 512 + 2 * 64 * 512) {
    int o = idx - 2 * 512 * 512;
    int ib = o >> 15;
    int rem = o & 32767;
    int dd = rem >> 9, h = rem & 511;
    W3T[o] = W3[ib * 32768 + h * 64 + dd];
  } else if (idx < 2 * 512 * 512 + 2 * 64 * 512 + 2 * 512 * 64) {
    int o = idx - (2 * 512 * 512 + 2 * 64 * 512);
    int ib = o >> 15;
    int rem = o & 32767;
    int k = rem >> 6, i = rem & 63;
    W1yT[o] = W1[ib * 81 * 512 + i * 512 + k];
  }
}

extern "C" void kernel_launch(void* const* d_in, const int* in_sizes, int n_in,
                              void* d_out, int out_size, void* d_ws, size_t ws_size,
                              hipStream_t stream) {
  (void)in_sizes; (void)n_in; (void)out_size; (void)ws_size;
  const float* x    = (const float*)d_in[0];
  const float* cond = (const float*)d_in[1];
  const float* eps  = (const float*)d_in[2];
  const float* W1   = (const float*)d_in[3];
  const float* b1   = (const float*)d_in[4];
  const float* W2   = (const float*)d_in[5];
  const float* b2   = (const float*)d_in[6];
  const float* W3   = (const float*)d_in[7];
  const float* b3   = (const float*)d_in[8];
  float* out = (float*)d_out;

  float* W2T  = (float*)d_ws;                    // 2*512*512
  float* W3T  = W2T + 2 * 512 * 512;             // 2*64*512
  float* W1yT = W3T + 2 * 64 * 512;              // 2*512*64

  const int total_t = 2 * 512 * 512 + 2 * 64 * 512 + 2 * 512 * 64;  // 655360
  transpose_prep<<<(total_t + 255) / 256, 256, 0, stream>>>(W1, W2, W3, W2T, W3T, W1yT);
  ffjord_kernel<<<4096 / ROWS, NT, 0, stream>>>(x, cond, eps, W1, b1, W2, b2, W3, b3,
                                                W2T, W3T, W1yT, out);
}

// Round 2
// 2972.268 us; speedup vs baseline: 4.1494x; 4.1494x over previous
//
#include <hip/hip_runtime.h>

// FFJORD B=4096 D=64 C=16 H=512, NBIJ=2, NSTEPS=8 RK4 -> 64 sequential MLP+VJP evals.
// Round 2: bf16 MFMA (16x16x32) version. M=16 rows/block, grid=256 (1 block/CU),
// 512 threads = 8 waves, each wave owns a 64-wide N-strip of the H=512 GEMMs.
// Weights pre-converted to bf16 column-major (N-major) in d_ws by prep kernel so
// B-fragments are contiguous 16B loads. L2-BW floor ~0.62 ms.

typedef __attribute__((ext_vector_type(8))) short short8;
typedef __attribute__((ext_vector_type(4))) float f32x4;

#define MFMA_B16(a, b, c) __builtin_amdgcn_mfma_f32_16x16x32_bf16((a), (b), (c), 0, 0, 0)

__device__ __forceinline__ unsigned short f2bf(float f) {
  union { float f; unsigned u; } v; v.f = f;
  return (unsigned short)((v.u + 0x7FFFu + ((v.u >> 16) & 1u)) >> 16);
}
__device__ __forceinline__ float bf2f(unsigned short u) {
  union { unsigned u; float f; } v; v.u = ((unsigned)u) << 16; return v.f;
}

// ws layout (ushort units), all bf16 column-major W[n][k]:
// W1f [2][512][96]  @ 0        (k>=81 zero-padded)
// W2f [2][512][512] @ 98304    (= W2^T elements: forward B operand)
// W2b [2][512][512] @ 622592   (= plain W2: backward B operand, i.e. (W2^T) col-major)
// W3f [2][64][512]  @ 1146880  (= W3^T: forward B)
// W3b [2][512][64]  @ 1212416  (= plain W3: backward B)
// W1y [2][64][512]  @ 1277952  (= first 64 rows of W1: B for gz GEMM)

__global__ void prep_bf16(const float* __restrict__ W1, const float* __restrict__ W2,
                          const float* __restrict__ W3, unsigned short* __restrict__ ws) {
  int o = blockIdx.x * 256 + threadIdx.x;
  if (o < 98304) {                       // W1f
    int ib = o / 49152, r = o % 49152, n = r / 96, k = r % 96;
    ws[o] = (k < 81) ? f2bf(W1[(size_t)ib * 41472 + k * 512 + n]) : (unsigned short)0;
  } else if (o < 622592) {               // W2f = W2 transposed
    int o2 = o - 98304;
    int ib = o2 / 262144, r = o2 % 262144, n = r / 512, k = r % 512;
    ws[o] = f2bf(W2[(size_t)ib * 262144 + k * 512 + n]);
  } else if (o < 1146880) {              // W2b = plain W2
    ws[o] = f2bf(W2[o - 622592]);
  } else if (o < 1212416) {              // W3f = W3 transposed
    int o2 = o - 1146880;
    int ib = o2 / 32768, r = o2 % 32768, n = r / 512, k = r % 512;
    ws[o] = f2bf(W3[(size_t)ib * 32768 + k * 64 + n]);
  } else if (o < 1277952) {              // W3b = plain W3
    ws[o] = f2bf(W3[o - 1212416]);
  } else if (o < 1343488) {              // W1y = first 64 rows of W1
    int o2 = o - 1277952;
    int ib = o2 / 32768, r = o2 % 32768, n = r / 512, k = r % 512;
    ws[o] = f2bf(W1[(size_t)ib * 41472 + n * 512 + k]);
  }
}

// A-buffer strides (bf16 elems): +8 padding -> bank stride 4 dwords -> 2-way aliasing (free)
#define ZS 104   // z: K=96 used
#define HS 520   // h buffers: K=512
#define ES 72    // eps: K=64

__global__ __launch_bounds__(512) void ffjord_mfma(
    const float* __restrict__ x, const float* __restrict__ cond, const float* __restrict__ eps,
    const float* __restrict__ b1g, const float* __restrict__ b2g, const float* __restrict__ b3g,
    const unsigned short* __restrict__ ws, float* __restrict__ out) {
  __shared__ unsigned short zA[16 * ZS];
  __shared__ unsigned short h1A[16 * HS];   // h1 bf16; overwritten by g1 in GEMM4b
  __shared__ unsigned short h2A[16 * HS];
  __shared__ unsigned short g2A[16 * HS];
  __shared__ unsigned short epsA[16 * ES];
  __shared__ float eps_s[16][64];
  __shared__ float f_s[16][64];
  __shared__ float ycur[16][64], ytmp[16][64], yacc[16][64];
  __shared__ float l_row[16], ld_row[16], ldacc[16];

  const int t = threadIdx.x;
  const int wave = t >> 6;
  const int lane = t & 63;
  const int lane15 = lane & 15;
  const int q8 = (lane >> 4) * 8;       // A/B frag k-offset; quad*4 = q8>>1 for C/D rows
  const int row0 = blockIdx.x * 16;

  // init state + constant z region (cond at k=64..79, zeros 80..95; 80 overwritten by te)
  for (int e = t; e < 1024; e += 512) {
    int m = e >> 6, d = e & 63;
    float xv = x[(size_t)(row0 + m) * 64 + d];
    ycur[m][d] = xv; ytmp[m][d] = xv;
  }
  {
    int m = t >> 5, kk = t & 31;
    zA[m * ZS + 64 + kk] = (kk < 16) ? f2bf(cond[(size_t)(row0 + m) * 16 + kk]) : (unsigned short)0;
  }
  if (t < 16) ld_row[t] = 0.f;

  const float dt = 0.125f;
  const float w06 = dt / 6.f, w13 = dt / 3.f;

  for (int ib = 0; ib < 2; ++ib) {
    const unsigned short* W1f = ws + 0       + ib * 49152;
    const unsigned short* W2f = ws + 98304   + ib * 262144;
    const unsigned short* W2b = ws + 622592  + ib * 262144;
    const unsigned short* W3f = ws + 1146880 + ib * 32768;
    const unsigned short* W3b = ws + 1212416 + ib * 32768;
    const unsigned short* W1y = ws + 1277952 + ib * 32768;
    const float* b1b = b1g + ib * 512;
    const float* b2b = b2g + ib * 512;
    const float* b3b = b3g + ib * 64;

    for (int e = t; e < 1024; e += 512) {
      int m = e >> 6, d = e & 63;
      float ev = eps[((size_t)ib * 4096 + row0 + m) * 64 + d];
      eps_s[m][d] = ev;
      epsA[m * ES + d] = f2bf(ev);
    }
    __syncthreads();

    for (int it = 0; it < 32; ++it) {
      const int step = it >> 2, s = it & 3;
      const float te = step * dt + ((s == 0) ? 0.f : (s == 3) ? dt : 0.5f * dt);

      // ---- z build + zero accumulators ----
      for (int e = t; e < 1024; e += 512) {
        int m = e >> 6, d = e & 63;
        zA[m * ZS + d] = f2bf(ytmp[m][d]);
        f_s[m][d] = 0.f;
      }
      if (t < 16) { zA[t * ZS + 80] = f2bf(te); l_row[t] = 0.f; }
      __syncthreads();

      // ---- GEMM1: h1 = tanh(z @ W1 + b1), K=96(pad), N=512 ----
      {
        f32x4 a0 = {0,0,0,0}, a1 = {0,0,0,0}, a2 = {0,0,0,0}, a3 = {0,0,0,0};
        const unsigned short* ap = zA + lane15 * ZS + q8;
        const unsigned short* wp = W1f + (size_t)(wave * 64 + lane15) * 96 + q8;
        #pragma unroll
        for (int k0 = 0; k0 < 96; k0 += 32) {
          short8 a = *(const short8*)(ap + k0);
          a0 = MFMA_B16(a, *(const short8*)(wp + k0),           a0);
          a1 = MFMA_B16(a, *(const short8*)(wp + 16 * 96 + k0), a1);
          a2 = MFMA_B16(a, *(const short8*)(wp + 32 * 96 + k0), a2);
          a3 = MFMA_B16(a, *(const short8*)(wp + 48 * 96 + k0), a3);
        }
        f32x4 acc[4] = {a0, a1, a2, a3};
        #pragma unroll
        for (int tl = 0; tl < 4; ++tl) {
          int n = wave * 64 + tl * 16 + lane15;
          float bias = b1b[n];
          #pragma unroll
          for (int rg = 0; rg < 4; ++rg) {
            int m = (q8 >> 1) + rg;
            h1A[m * HS + n] = f2bf(tanhf(acc[tl][rg] + bias));
          }
        }
      }
      __syncthreads();

      // ---- GEMM2: h2 = tanh(h1 @ W2 + b2), K=512, N=512 ----
      {
        f32x4 a0 = {0,0,0,0}, a1 = {0,0,0,0}, a2 = {0,0,0,0}, a3 = {0,0,0,0};
        const unsigned short* ap = h1A + lane15 * HS + q8;
        const unsigned short* wp = W2f + (size_t)(wave * 64 + lane15) * 512 + q8;
        #pragma unroll 4
        for (int k0 = 0; k0 < 512; k0 += 32) {
          short8 a = *(const short8*)(ap + k0);
          a0 = MFMA_B16(a, *(const short8*)(wp + k0),            a0);
          a1 = MFMA_B16(a, *(const short8*)(wp + 16 * 512 + k0), a1);
          a2 = MFMA_B16(a, *(const short8*)(wp + 32 * 512 + k0), a2);
          a3 = MFMA_B16(a, *(const short8*)(wp + 48 * 512 + k0), a3);
        }
        f32x4 acc[4] = {a0, a1, a2, a3};
        #pragma unroll
        for (int tl = 0; tl < 4; ++tl) {
          int n = wave * 64 + tl * 16 + lane15;
          float bias = b2b[n];
          #pragma unroll
          for (int rg = 0; rg < 4; ++rg) {
            int m = (q8 >> 1) + rg;
            h2A[m * HS + n] = f2bf(tanhf(acc[tl][rg] + bias));
          }
        }
      }
      __syncthreads();

      // ---- GEMM3f: f += h2 @ W3 (N=64, K split across waves, LDS-atomic reduce) ----
      {
        f32x4 a0 = {0,0,0,0}, a1 = {0,0,0,0}, a2 = {0,0,0,0}, a3 = {0,0,0,0};
        const unsigned short* ap = h2A + lane15 * HS + wave * 64 + q8;
        const unsigned short* wp = W3f + (size_t)lane15 * 512 + wave * 64 + q8;
        #pragma unroll
        for (int kk = 0; kk < 64; kk += 32) {
          short8 a = *(const short8*)(ap + kk);
          a0 = MFMA_B16(a, *(const short8*)(wp + kk),            a0);
          a1 = MFMA_B16(a, *(const short8*)(wp + 16 * 512 + kk), a1);
          a2 = MFMA_B16(a, *(const short8*)(wp + 32 * 512 + kk), a2);
          a3 = MFMA_B16(a, *(const short8*)(wp + 48 * 512 + kk), a3);
        }
        f32x4 acc[4] = {a0, a1, a2, a3};
        #pragma unroll
        for (int tl = 0; tl < 4; ++tl) {
          int n = tl * 16 + lane15;
          #pragma unroll
          for (int rg = 0; rg < 4; ++rg)
            atomicAdd(&f_s[(q8 >> 1) + rg][n], acc[tl][rg]);
        }
      }
      // ---- GEMM3b: g2 = (eps @ W3^T) * (1 - h2^2), N=512, K=64 ----
      {
        f32x4 a0 = {0,0,0,0}, a1 = {0,0,0,0}, a2 = {0,0,0,0}, a3 = {0,0,0,0};
        const unsigned short* ap = epsA + lane15 * ES + q8;
        const unsigned short* wp = W3b + (size_t)(wave * 64 + lane15) * 64 + q8;
        #pragma unroll
        for (int kk = 0; kk < 64; kk += 32) {
          short8 a = *(const short8*)(ap + kk);
          a0 = MFMA_B16(a, *(const short8*)(wp + kk),           a0);
          a1 = MFMA_B16(a, *(const short8*)(wp + 16 * 64 + kk), a1);
          a2 = MFMA_B16(a, *(const short8*)(wp + 32 * 64 + kk), a2);
          a3 = MFMA_B16(a, *(const short8*)(wp + 48 * 64 + kk), a3);
        }
        f32x4 acc[4] = {a0, a1, a2, a3};
        #pragma unroll
        for (int tl = 0; tl < 4; ++tl) {
          int n = wave * 64 + tl * 16 + lane15;
          #pragma unroll
          for (int rg = 0; rg < 4; ++rg) {
            int m = (q8 >> 1) + rg;
            float h = bf2f(h2A[m * HS + n]);
            g2A[m * HS + n] = f2bf(acc[tl][rg] * (1.f - h * h));
          }
        }
      }
      __syncthreads();

      // ---- GEMM4b: g1 = (g2 @ W2^T) * (1 - h1^2) -> h1A in place ----
      {
        f32x4 a0 = {0,0,0,0}, a1 = {0,0,0,0}, a2 = {0,0,0,0}, a3 = {0,0,0,0};
        const unsigned short* ap = g2A + lane15 * HS + q8;
        const unsigned short* wp = W2b + (size_t)(wave * 64 + lane15) * 512 + q8;
        #pragma unroll 4
        for (int k0 = 0; k0 < 512; k0 += 32) {
          short8 a = *(const short8*)(ap + k0);
          a0 = MFMA_B16(a, *(const short8*)(wp + k0),            a0);
          a1 = MFMA_B16(a, *(const short8*)(wp + 16 * 512 + k0), a1);
          a2 = MFMA_B16(a, *(const short8*)(wp + 32 * 512 + k0), a2);
          a3 = MFMA_B16(a, *(const short8*)(wp + 48 * 512 + k0), a3);
        }
        f32x4 acc[4] = {a0, a1, a2, a3};
        #pragma unroll
        for (int tl = 0; tl < 4; ++tl) {
          int n = wave * 64 + tl * 16 + lane15;
          #pragma unroll
          for (int rg = 0; rg < 4; ++rg) {
            int m = (q8 >> 1) + rg;
            float h = bf2f(h1A[m * HS + n]);
            h1A[m * HS + n] = f2bf(acc[tl][rg] * (1.f - h * h));
          }
        }
      }
      __syncthreads();

      // ---- GEMM5b: gz = g1 @ W1y^T (N=64, K split), l = sum(gz*eps) ----
      {
        f32x4 a0 = {0,0,0,0}, a1 = {0,0,0,0}, a2 = {0,0,0,0}, a3 = {0,0,0,0};
        const unsigned short* ap = h1A + lane15 * HS + wave * 64 + q8;
        const unsigned short* wp = W1y + (size_t)lane15 * 512 + wave * 64 + q8;
        #pragma unroll
        for (int kk = 0; kk < 64; kk += 32) {
          short8 a = *(const short8*)(ap + kk);
          a0 = MFMA_B16(a, *(const short8*)(wp + kk),            a0);
          a1 = MFMA_B16(a, *(const short8*)(wp + 16 * 512 + kk), a1);
          a2 = MFMA_B16(a, *(const short8*)(wp + 32 * 512 + kk), a2);
          a3 = MFMA_B16(a, *(const short8*)(wp + 48 * 512 + kk), a3);
        }
        f32x4 acc[4] = {a0, a1, a2, a3};
        #pragma unroll
        for (int rg = 0; rg < 4; ++rg) {
          int m = (q8 >> 1) + rg;
          float p = acc[0][rg] * eps_s[m][lane15]
                  + acc[1][rg] * eps_s[m][16 + lane15]
                  + acc[2][rg] * eps_s[m][32 + lane15]
                  + acc[3][rg] * eps_s[m][48 + lane15];
          #pragma unroll
          for (int o = 1; o < 16; o <<= 1) p += __shfl_xor(p, o);
          if (lane15 == 0) atomicAdd(&l_row[m], p);
        }
      }
      __syncthreads();

      // ---- RK4 update ----
      {
        const float wk = (s == 0 || s == 3) ? w06 : w13;
        for (int e = t; e < 1024; e += 512) {
          int m = e >> 6, d = e & 63;
          float fv = f_s[m][d] + b3b[d];
          if (s == 0)      yacc[m][d] = ycur[m][d] + w06 * fv;
          else if (s < 3)  yacc[m][d] += wk * fv;
          if (s < 3) {
            ytmp[m][d] = ycur[m][d] + ((s == 2) ? dt : 0.5f * dt) * fv;
          } else {
            float yn = yacc[m][d] + w06 * fv;
            ycur[m][d] = yn; ytmp[m][d] = yn;
          }
        }
        if (t < 16) {
          float lv = l_row[t];
          if (s == 0)      ldacc[t] = w06 * lv;
          else if (s < 3)  ldacc[t] += wk * lv;
          else             ld_row[t] += ldacc[t] + w06 * lv;
        }
      }
      __syncthreads();
    }
  }

  for (int e = t; e < 1024; e += 512) {
    int m = e >> 6, d = e & 63;
    out[(size_t)(row0 + m) * 65 + d] = ycur[m][d];
  }
  if (t < 16) out[(size_t)(row0 + t) * 65 + 64] = ld_row[t];
}

extern "C" void kernel_launch(void* const* d_in, const int* in_sizes, int n_in,
                              void* d_out, int out_size, void* d_ws, size_t ws_size,
                              hipStream_t stream) {
  (void)in_sizes; (void)n_in; (void)out_size; (void)ws_size;
  const float* x    = (const float*)d_in[0];
  const float* cond = (const float*)d_in[1];
  const float* eps  = (const float*)d_in[2];
  const float* W1   = (const float*)d_in[3];
  const float* b1   = (const float*)d_in[4];
  const float* W2   = (const float*)d_in[5];
  const float* b2   = (const float*)d_in[6];
  const float* W3   = (const float*)d_in[7];
  const float* b3   = (const float*)d_in[8];
  float* out = (float*)d_out;
  unsigned short* ws = (unsigned short*)d_ws;

  const int prep_total = 1343488;
  prep_bf16<<<(prep_total + 255) / 256, 256, 0, stream>>>(W1, W2, W3, ws);
  ffjord_mfma<<<256, 512, 0, stream>>>(x, cond, eps, b1, b2, b3, ws, out);
}